// Round 10
// baseline (9181.633 us; speedup 1.0000x reference)
//
#include <hip/hip_runtime.h>
#include <hip/hip_bf16.h>
#include <cstdint>

typedef __bf16 bf16_t;
typedef __bf16 bf16x8 __attribute__((ext_vector_type(8)));
typedef float  f32x4  __attribute__((ext_vector_type(4)));
typedef unsigned long long u64;
typedef unsigned int u32;
typedef unsigned short u16;

#define T_SEQ 512
#define TAGMASK 0x0000FFFF0000FFFFull

#define MFMA(a, b, c) __builtin_amdgcn_mfma_f32_16x16x32_bf16((a), (b), (c), 0, 0, 0)

static __device__ __forceinline__ u64 ldA8(const u64* p) {
  return __hip_atomic_load(p, __ATOMIC_RELAXED, __HIP_MEMORY_SCOPE_AGENT);
}
static __device__ __forceinline__ bf16x8 ld16(const bf16_t* p) {
  return *(const bf16x8*)p;
}
static __device__ __forceinline__ float sigm(float x) {
  return __builtin_amdgcn_rcpf(1.f + __expf(-x));
}
static __device__ __forceinline__ float tanh_f(float x) {
  return 2.f * __builtin_amdgcn_rcpf(1.f + __expf(-2.f * x)) - 1.f;
}

// ---------------- gather + convert: xe[t*64+b][512] = bf16(emb[x[b,t]]) ----------------
__global__ void gather_xe(const int* __restrict__ x, const float* __restrict__ emb,
                          bf16_t* __restrict__ xe) {
  const int row = blockIdx.x;            // row = t*64 + b
  const int b = row & 63, t = row >> 6;
  const int tok = x[b * 512 + t];        // x is [B][T]
  const float4* src = (const float4*)(emb + (size_t)tok * 512);
  float4 a = src[threadIdx.x * 2], c = src[threadIdx.x * 2 + 1];
  bf16x8 v;
  v[0] = (bf16_t)a.x; v[1] = (bf16_t)a.y; v[2] = (bf16_t)a.z; v[3] = (bf16_t)a.w;
  v[4] = (bf16_t)c.x; v[5] = (bf16_t)c.y; v[6] = (bf16_t)c.z; v[7] = (bf16_t)c.w;
  *(bf16x8*)(xe + (size_t)row * 512 + threadIdx.x * 8) = v;
}

// ---------------- f32 -> bf16 convert (8 elems/thread) ----------------
__global__ void cvt_f32_bf16(const float* __restrict__ s, bf16_t* __restrict__ d, int n8) {
  int i = blockIdx.x * blockDim.x + threadIdx.x;
  if (i >= n8) return;
  const float4* sp = (const float4*)s;
  float4 a = sp[2 * (size_t)i], b = sp[2 * (size_t)i + 1];
  bf16x8 v;
  v[0] = (bf16_t)a.x; v[1] = (bf16_t)a.y; v[2] = (bf16_t)a.z; v[3] = (bf16_t)a.w;
  v[4] = (bf16_t)b.x; v[5] = (bf16_t)b.y; v[6] = (bf16_t)b.z; v[7] = (bf16_t)b.w;
  *(bf16x8*)(d + 8 * (size_t)i) = v;
}

// ---------------- persistent sequential LSTM: tagged-h self-sync ----------------
// 4 cliques x 16 batches (recurrence-independent); per clique 64 WGs x 16 cols; 8 waves
// K-split (h:128, xe:64 each). h stored as u32 words (bf16<<16 | step_tag) in [2] slots:
// a 4B store is atomic, so data+tag travel together. Producers (wave0) just fire 4 tagged
// stores -- no drain, no flags, no fanout barrier. Consumers (every wave) retry-load their
// own 16x8B A-slice until all 32 tags == t: the load IS the sync. One __syncthreads per
// step (partials reduce); red_s reuse is ordered by the tag dependency itself.
__global__ __launch_bounds__(512, 1) void lstm_seq(
    const bf16_t* __restrict__ xe,       // [512*64][512]
    const bf16_t* __restrict__ wihb,     // [4096][512] bf16
    const float* __restrict__ whh,       // [4096][1024] f32
    const float* __restrict__ bih, const float* __restrict__ bhh,
    const float* __restrict__ wfc, const float* __restrict__ bfc,
    u32* __restrict__ hw,                // [2][64][1024] tagged h; slot0 pre-zeroed (tag0=h(0))
    float* __restrict__ out) {
  __shared__ bf16_t whh_s[64][1032];     // 132,096 B
  __shared__ f32x4 red_s[7][4][64];      //  28,672 B  (total 160,768 <= 163,840)
  const int tid = threadIdx.x, bid = blockIdx.x;
  const int lane = tid & 63, w = tid >> 6;
  const int clq = (bid & 7) >> 1;                     // XCD-pair clique (locality heuristic)
  const int colg = ((bid >> 3) << 1) | (bid & 1);     // 0..63

  // ---- stage W_hh slice f32 -> bf16 (one-time): local row r = gate*16 + c ----
  {
    const int r = tid >> 3, sub = tid & 7;            // 64 rows x 8 chunks of 128 f32
    const int grow = (r >> 4) * 1024 + colg * 16 + (r & 15);
    const float4* s = (const float4*)(whh + (size_t)grow * 1024 + sub * 128);
    bf16_t* d = &whh_s[r][sub * 128];
#pragma unroll 8
    for (int u = 0; u < 32; ++u) {
      float4 f = s[u];
      d[u * 4 + 0] = (bf16_t)f.x; d[u * 4 + 1] = (bf16_t)f.y;
      d[u * 4 + 2] = (bf16_t)f.z; d[u * 4 + 3] = (bf16_t)f.w;
    }
  }
  __syncthreads();

  const int rloc = lane & 15, kg = lane >> 4;
  const int col = colg * 16 + rloc;      // B-row / store column
  const int brow = clq * 16 + rloc;      // A-row (global batch)

  const float bI = bih[col] + bhh[col];
  const float bF = bih[1024 + col] + bhh[1024 + col];
  const float bG = bih[2048 + col] + bhh[2048 + col];
  const float bO = bih[3072 + col] + bhh[3072 + col];

  // B-frag bases: this wave's K-slice (xe: w*64, h: w*128)
  const bf16_t* wB0 = wihb + ((size_t)(0 * 1024 + col)) * 512 + w * 64 + kg * 8;
  const bf16_t* wB1 = wihb + ((size_t)(1 * 1024 + col)) * 512 + w * 64 + kg * 8;
  const bf16_t* wB2 = wihb + ((size_t)(2 * 1024 + col)) * 512 + w * 64 + kg * 8;
  const bf16_t* wB3 = wihb + ((size_t)(3 * 1024 + col)) * 512 + w * 64 + kg * 8;
  const bf16_t* hB0 = &whh_s[ 0 + rloc][w * 128 + kg * 8];
  const bf16_t* hB1 = &whh_s[16 + rloc][w * 128 + kg * 8];
  const bf16_t* hB2 = &whh_s[32 + rloc][w * 128 + kg * 8];
  const bf16_t* hB3 = &whh_s[48 + rloc][w * 128 + kg * 8];

  float cs[4] = {0.f, 0.f, 0.f, 0.f};   // cell state (wave0 lanes only)

  for (int t = 0; t < T_SEQ; ++t) {
    f32x4 A0 = {0.f, 0.f, 0.f, 0.f}, A1 = A0, A2 = A0, A3 = A0;  // i,f,g,o partials

    // ---- xe[t] @ Wih^T (own K-slice of 64): pure program-order prelude ----
    const bf16_t* ax = xe + ((size_t)t * 64 + brow) * 512 + w * 64 + kg * 8;
#pragma unroll
    for (int kk = 0; kk < 2; ++kk) {
      bf16x8 a = ld16(ax + kk * 32);
      A0 = MFMA(a, ld16(wB0 + kk * 32), A0);
      A1 = MFMA(a, ld16(wB1 + kk * 32), A1);
      A2 = MFMA(a, ld16(wB2 + kk * 32), A2);
      A3 = MFMA(a, ld16(wB3 + kk * 32), A3);
    }

    // ---- tagged h(t) self-sync load: 16 x 8B coherent loads, retry until tags==t ----
    const u64* hp = (const u64*)hw + (size_t)(t & 1) * 32768 +
                    (size_t)brow * 512 + w * 64 + kg * 4;
    u64 d0, d1, d2, d3, d4, d5, d6, d7, d8, d9, da, db, dc, dd, de, df;
    {
      const u64 tagpat = (u64)(u32)t * 0x0000000100000001ull;
      for (;;) {
        d0 = ldA8(hp +  0); d1 = ldA8(hp +  1); d2 = ldA8(hp +  2); d3 = ldA8(hp +  3);
        d4 = ldA8(hp + 16); d5 = ldA8(hp + 17); d6 = ldA8(hp + 18); d7 = ldA8(hp + 19);
        d8 = ldA8(hp + 32); d9 = ldA8(hp + 33); da = ldA8(hp + 34); db = ldA8(hp + 35);
        dc = ldA8(hp + 48); dd = ldA8(hp + 49); de = ldA8(hp + 50); df = ldA8(hp + 51);
        u64 diff = ((d0 ^ tagpat) | (d1 ^ tagpat) | (d2 ^ tagpat) | (d3 ^ tagpat) |
                    (d4 ^ tagpat) | (d5 ^ tagpat) | (d6 ^ tagpat) | (d7 ^ tagpat) |
                    (d8 ^ tagpat) | (d9 ^ tagpat) | (da ^ tagpat) | (db ^ tagpat) |
                    (dc ^ tagpat) | (dd ^ tagpat) | (de ^ tagpat) | (df ^ tagpat)) & TAGMASK;
        if (__all(diff == 0)) break;
        __builtin_amdgcn_s_sleep(2);
      }
    }

    // ---- h(t) @ Whh^T: extract bf16 pairs, MFMA against LDS B-frags ----
#define HKK(kk, e0, e1, e2, e3)                                                  \
    {                                                                            \
      union { u32 u[4]; bf16x8 v; } a;                                           \
      a.u[0] = (u32)((e0 >> 16) & 0xFFFFu) | (u32)((e0 >> 48) << 16);            \
      a.u[1] = (u32)((e1 >> 16) & 0xFFFFu) | (u32)((e1 >> 48) << 16);            \
      a.u[2] = (u32)((e2 >> 16) & 0xFFFFu) | (u32)((e2 >> 48) << 16);            \
      a.u[3] = (u32)((e3 >> 16) & 0xFFFFu) | (u32)((e3 >> 48) << 16);            \
      A0 = MFMA(a.v, ld16(hB0 + kk * 32), A0);                                   \
      A1 = MFMA(a.v, ld16(hB1 + kk * 32), A1);                                   \
      A2 = MFMA(a.v, ld16(hB2 + kk * 32), A2);                                   \
      A3 = MFMA(a.v, ld16(hB3 + kk * 32), A3);                                   \
    }
    HKK(0, d0, d1, d2, d3)
    HKK(1, d4, d5, d6, d7)
    HKK(2, d8, d9, da, db)
    HKK(3, dc, dd, de, df)
#undef HKK

    // ---- K-reduce: waves 1-7 dump partials; wave0 sums after the (only) barrier ----
    if (w) {
      red_s[w - 1][0][lane] = A0; red_s[w - 1][1][lane] = A1;
      red_s[w - 1][2][lane] = A2; red_s[w - 1][3][lane] = A3;
    }
    __syncthreads();
    if (w == 0) {
#pragma unroll
      for (int q = 0; q < 7; ++q) {
        A0 += red_s[q][0][lane]; A1 += red_s[q][1][lane];
        A2 += red_s[q][2][lane]; A3 += red_s[q][3][lane];
      }
      // ---- elementwise + tagged h-store (fire and forget; tag IS the signal) ----
      u32* hn = hw + (size_t)((t + 1) & 1) * 65536 +
                (size_t)(clq * 16 + kg * 4) * 1024 + col;
      const u32 tag = (u32)(t + 1);
#pragma unroll
      for (int r = 0; r < 4; ++r) {
        const float gi = A0[r] + bI, gf = A1[r] + bF, gg = A2[r] + bG, go = A3[r] + bO;
        const float ii = sigm(gi), ff = sigm(gf), oo = sigm(go);
        cs[r] = ff * cs[r] + ii * tanh_f(gg);
        const float hv = oo * tanh_f(cs[r]);
        const bf16_t hvb = (bf16_t)hv;
        const u32 word = ((u32)__builtin_bit_cast(u16, hvb) << 16) | tag;
        __hip_atomic_store(hn + (size_t)r * 1024, word,
                           __ATOMIC_RELAXED, __HIP_MEMORY_SCOPE_AGENT);
      }
    }
    // red_s reuse ordering: waves 1-7 can only dump step t+1 after their h(t+1) tag-loads
    // succeed, which requires wave0's stores, which follow wave0's red_s reads. No barrier.
  }

  // ---- final FC + sigmoid: colg 0 WG of each clique, tag-checked reads of h(512) ----
  if (colg != 0) return;
  if (tid < 64) {
    const int bth = tid >> 2, part = tid & 3;          // 16 batches x 4 parts of 256 cols
    const int gb = clq * 16 + bth;
    const u64* hp = (const u64*)hw + (size_t)gb * 512 + part * 128;  // slot (512&1)=0
    const float* wp = wfc + part * 256;
    const u64 tagpat = (u64)(u32)T_SEQ * 0x0000000100000001ull;
    float s = 0.f;
    for (int blk = 0; blk < 16; ++blk) {               // 16 x 8 u64 = 128 u64 = 256 cols
      u64 d[8];
      for (;;) {
        u64 diff = 0;
#pragma unroll
        for (int i = 0; i < 8; ++i) {
          d[i] = ldA8(hp + blk * 8 + i);
          diff |= (d[i] ^ tagpat) & TAGMASK;
        }
        if (diff == 0) break;
        __builtin_amdgcn_s_sleep(2);
      }
#pragma unroll
      for (int i = 0; i < 8; ++i) {
        const float h0 = (float)__builtin_bit_cast(bf16_t, (u16)((d[i] >> 16) & 0xFFFFu));
        const float h1 = (float)__builtin_bit_cast(bf16_t, (u16)(d[i] >> 48));
        s += h0 * wp[blk * 16 + 2 * i] + h1 * wp[blk * 16 + 2 * i + 1];
      }
    }
    s += __shfl_xor(s, 1);
    s += __shfl_xor(s, 2);
    if (part == 0) out[gb] = sigm(s + bfc[0]);
  }
}

extern "C" void kernel_launch(void* const* d_in, const int* in_sizes, int n_in,
                              void* d_out, int out_size, void* d_ws, size_t ws_size,
                              hipStream_t stream) {
  const int* x = (const int*)d_in[0];
  const float* emb = (const float*)d_in[1];
  const float* wih = (const float*)d_in[2];
  const float* whh = (const float*)d_in[3];
  const float* bih = (const float*)d_in[4];
  const float* bhh = (const float*)d_in[5];
  const float* wfc = (const float*)d_in[6];
  const float* bfc = (const float*)d_in[7];
  float* out = (float*)d_out;

  char* ws = (char*)d_ws;
  bf16_t* xe = (bf16_t*)ws;                                    // 33,554,432 B
  bf16_t* wihb = (bf16_t*)(ws + 33554432);                     //  4,194,304 B
  u32* hw = (u32*)(ws + 33554432 + 4194304);                   //    524,288 B (2 slots)

  // slot0 = h(0)=0 with tag 0 (memset gives both); slot1 stale tags never match.
  hipMemsetAsync(hw, 0, 262144, stream);
  gather_xe<<<32768, 64, 0, stream>>>(x, emb, xe);
  cvt_f32_bf16<<<1024, 256, 0, stream>>>(wih, wihb, 262144);

  void* args[] = {(void*)&xe, (void*)&wihb, (void*)&whh, (void*)&bih, (void*)&bhh,
                  (void*)&wfc, (void*)&bfc, (void*)&hw, (void*)&out};
  hipLaunchCooperativeKernel((const void*)lstm_seq, dim3(256), dim3(512), args, 0, stream);
}

// Round 11
// 4087.590 us; speedup vs baseline: 2.2462x; 2.2462x over previous
//
#include <hip/hip_runtime.h>
#include <hip/hip_bf16.h>
#include <cstdint>

typedef __bf16 bf16_t;
typedef __bf16 bf16x8 __attribute__((ext_vector_type(8)));
typedef float  f32x4  __attribute__((ext_vector_type(4)));
typedef unsigned long long u64;
typedef unsigned int u32;
typedef unsigned short u16;

#define T_SEQ 512
#define HROT  64    // h-buffer rotation depth

#define MFMA(a, b, c) __builtin_amdgcn_mfma_f32_16x16x32_bf16((a), (b), (c), 0, 0, 0)

static __device__ __forceinline__ u64 ldA8(const u64* p) {
  return __hip_atomic_load(p, __ATOMIC_RELAXED, __HIP_MEMORY_SCOPE_AGENT);
}
static __device__ __forceinline__ bf16x8 ld16(const bf16_t* p) {
  return *(const bf16x8*)p;
}

// ---------------- gather + convert: xe[t*64+b][512] = bf16(emb[x[b,t]]) ----------------
__global__ void gather_xe(const int* __restrict__ x, const float* __restrict__ emb,
                          bf16_t* __restrict__ xe) {
  const int row = blockIdx.x;            // row = t*64 + b
  const int b = row & 63, t = row >> 6;
  const int tok = x[b * 512 + t];        // x is [B][T]
  const float4* src = (const float4*)(emb + (size_t)tok * 512);
  float4 a = src[threadIdx.x * 2], c = src[threadIdx.x * 2 + 1];
  bf16x8 v;
  v[0] = (bf16_t)a.x; v[1] = (bf16_t)a.y; v[2] = (bf16_t)a.z; v[3] = (bf16_t)a.w;
  v[4] = (bf16_t)c.x; v[5] = (bf16_t)c.y; v[6] = (bf16_t)c.z; v[7] = (bf16_t)c.w;
  *(bf16x8*)(xe + (size_t)row * 512 + threadIdx.x * 8) = v;
}

// ---------------- f32 -> bf16 convert (8 elems/thread) ----------------
__global__ void cvt_f32_bf16(const float* __restrict__ s, bf16_t* __restrict__ d, int n8) {
  int i = blockIdx.x * blockDim.x + threadIdx.x;
  if (i >= n8) return;
  const float4* sp = (const float4*)s;
  float4 a = sp[2 * (size_t)i], b = sp[2 * (size_t)i + 1];
  bf16x8 v;
  v[0] = (bf16_t)a.x; v[1] = (bf16_t)a.y; v[2] = (bf16_t)a.z; v[3] = (bf16_t)a.w;
  v[4] = (bf16_t)b.x; v[5] = (bf16_t)b.y; v[6] = (bf16_t)b.z; v[7] = (bf16_t)b.w;
  *(bf16x8*)(d + 8 * (size_t)i) = v;
}

// ---------------- persistent sequential LSTM: cliques + per-wave subset polling ----------------
// 4 cliques x 16 batches (recurrence-independent); per clique 64 WGs x 16 cols; 8 waves
// K-split (h:128, xe:64 each). Wave w consumes h-cols [128w,128w+128) = producers
// colg' = 8w..8w+7, and polls ONLY those 8 flags (replicated-line coalesced load + __all):
// no relay wave, no fanout barrier -- each wave starts its h-load the moment its slice is
// ready. Producers: wave0 elementwise -> 4 agent-scope h-stores -> vmcnt(0) -> lane0 plain
// flag store (no RMW). h rotates through HROT buffers (plain nt loads fresh by construction).
__global__ __launch_bounds__(512, 1) void lstm_seq(
    const bf16_t* __restrict__ xe,       // [512*64][512]
    const bf16_t* __restrict__ wihb,     // [4096][512] bf16
    const float* __restrict__ whh,       // [4096][1024] f32
    const float* __restrict__ bih, const float* __restrict__ bhh,
    const float* __restrict__ wfc, const float* __restrict__ bfc,
    bf16_t* __restrict__ hb,             // [HROT][64][1024]; buffer 0 pre-zeroed
    u32* __restrict__ flags,             // [4][64], pre-zeroed
    float* __restrict__ out) {
  __shared__ bf16_t whh_s[64][1032];     // 132,096 B
  __shared__ f32x4 red_s[7][4][64];      //  28,672 B  (total 160,768 <= 163,840)
  const int tid = threadIdx.x, bid = blockIdx.x;
  const int lane = tid & 63, w = tid >> 6;
  const int clq = (bid & 7) >> 1;                     // XCD-pair clique (locality heuristic)
  const int colg = ((bid >> 3) << 1) | (bid & 1);     // 0..63
  u32* flg = flags + clq * 64;

  // ---- stage W_hh slice f32 -> bf16 (one-time): local row r = gate*16 + c ----
  {
    const int r = tid >> 3, sub = tid & 7;            // 64 rows x 8 chunks of 128 f32
    const int grow = (r >> 4) * 1024 + colg * 16 + (r & 15);
    const float4* s = (const float4*)(whh + (size_t)grow * 1024 + sub * 128);
    bf16_t* d = &whh_s[r][sub * 128];
#pragma unroll 8
    for (int u = 0; u < 32; ++u) {
      float4 f = s[u];
      d[u * 4 + 0] = (bf16_t)f.x; d[u * 4 + 1] = (bf16_t)f.y;
      d[u * 4 + 2] = (bf16_t)f.z; d[u * 4 + 3] = (bf16_t)f.w;
    }
  }
  __syncthreads();

  const int rloc = lane & 15, kg = lane >> 4;
  const int col = colg * 16 + rloc;      // B-row / store column
  const int brow = clq * 16 + rloc;      // A-row (global batch)

  const float bI = bih[col] + bhh[col];
  const float bF = bih[1024 + col] + bhh[1024 + col];
  const float bG = bih[2048 + col] + bhh[2048 + col];
  const float bO = bih[3072 + col] + bhh[3072 + col];

  // B-frag bases: this wave's K-slice (xe: w*64, h: w*128)
  const bf16_t* wB0 = wihb + ((size_t)(0 * 1024 + col)) * 512 + w * 64 + kg * 8;
  const bf16_t* wB1 = wihb + ((size_t)(1 * 1024 + col)) * 512 + w * 64 + kg * 8;
  const bf16_t* wB2 = wihb + ((size_t)(2 * 1024 + col)) * 512 + w * 64 + kg * 8;
  const bf16_t* wB3 = wihb + ((size_t)(3 * 1024 + col)) * 512 + w * 64 + kg * 8;
  const bf16_t* hB0 = &whh_s[ 0 + rloc][w * 128 + kg * 8];
  const bf16_t* hB1 = &whh_s[16 + rloc][w * 128 + kg * 8];
  const bf16_t* hB2 = &whh_s[32 + rloc][w * 128 + kg * 8];
  const bf16_t* hB3 = &whh_s[48 + rloc][w * 128 + kg * 8];

  // this wave's producer-subset flag pointer (8 producers, replicated across lanes)
  const u32* fsub = flg + w * 8 + (lane & 7);

  float cs[4] = {0.f, 0.f, 0.f, 0.f};   // cell state (wave0 lanes only)

  for (int t = 0; t < T_SEQ; ++t) {
    f32x4 A0 = {0.f, 0.f, 0.f, 0.f}, A1 = A0, A2 = A0, A3 = A0;  // i,f,g,o partials

    // ---- xe[t] @ Wih^T (own K-slice of 64): runs in the wait shadow ----
    const bf16_t* ax = xe + ((size_t)t * 64 + brow) * 512 + w * 64 + kg * 8;
#pragma unroll
    for (int kk = 0; kk < 2; ++kk) {
      bf16x8 a = ld16(ax + kk * 32);
      A0 = MFMA(a, ld16(wB0 + kk * 32), A0);
      A1 = MFMA(a, ld16(wB1 + kk * 32), A1);
      A2 = MFMA(a, ld16(wB2 + kk * 32), A2);
      A3 = MFMA(a, ld16(wB3 + kk * 32), A3);
    }

    // ---- wait for OWN slice of h(t): poll this wave's 8 producer flags ----
    if (t) {
      const u32 tgt = (u32)t;
      u32 v = __hip_atomic_load(fsub, __ATOMIC_RELAXED, __HIP_MEMORY_SCOPE_AGENT);
      while (!__all(v >= tgt)) {
        __builtin_amdgcn_s_sleep(1);
        v = __hip_atomic_load(fsub, __ATOMIC_RELAXED, __HIP_MEMORY_SCOPE_AGENT);
      }
      asm volatile("" ::: "memory");   // pin h loads below the poll exit
    }

    // ---- h(t) @ Whh^T (own K-slice of 128): plain nt loads, rotated buffer ----
    const bf16_t* ah = hb + (size_t)(t & (HROT - 1)) * 65536 +
                       (size_t)brow * 1024 + w * 128 + kg * 8;
#pragma unroll
    for (int kk = 0; kk < 4; ++kk) {
      bf16x8 a = __builtin_nontemporal_load((const bf16x8*)(ah + kk * 32));
      A0 = MFMA(a, ld16(hB0 + kk * 32), A0);
      A1 = MFMA(a, ld16(hB1 + kk * 32), A1);
      A2 = MFMA(a, ld16(hB2 + kk * 32), A2);
      A3 = MFMA(a, ld16(hB3 + kk * 32), A3);
    }

    // ---- K-reduce: waves 1-7 dump partials; wave0 sums between barriers ----
    if (w) {
      red_s[w - 1][0][lane] = A0; red_s[w - 1][1][lane] = A1;
      red_s[w - 1][2][lane] = A2; red_s[w - 1][3][lane] = A3;
    }
    __syncthreads();                     // #1: partials visible
    if (w == 0) {
#pragma unroll
      for (int q = 0; q < 7; ++q) {
        A0 += red_s[q][0][lane]; A1 += red_s[q][1][lane];
        A2 += red_s[q][2][lane]; A3 += red_s[q][3][lane];
      }
    }
    __syncthreads();                     // #2: wave0's red_s reads done -> safe next dump

    // ---- wave0: elementwise + h-store + drain + flag (others run ahead) ----
    if (w == 0) {
      u16* hn = (u16*)(hb + (size_t)((t + 1) & (HROT - 1)) * 65536) +
                (size_t)(clq * 16 + kg * 4) * 1024 + col;
#pragma unroll
      for (int r = 0; r < 4; ++r) {
        const float gi = A0[r] + bI, gf = A1[r] + bF, gg = A2[r] + bG, go = A3[r] + bO;
        const float ii = 1.f / (1.f + __expf(-gi));
        const float ff = 1.f / (1.f + __expf(-gf));
        const float gv = tanhf(gg);
        const float oo = 1.f / (1.f + __expf(-go));
        cs[r] = ff * cs[r] + ii * gv;
        const float hv = oo * tanhf(cs[r]);
        const bf16_t hvb = (bf16_t)hv;
        __hip_atomic_store(hn + (size_t)r * 1024, __builtin_bit_cast(u16, hvb),
                           __ATOMIC_RELAXED, __HIP_MEMORY_SCOPE_AGENT);
      }
      asm volatile("s_waitcnt vmcnt(0)" ::: "memory");  // only wave0 stores h
      if (lane == 0)
        __hip_atomic_store(flg + colg, (u32)(t + 1), __ATOMIC_RELAXED,
                           __HIP_MEMORY_SCOPE_AGENT);
    }
  }

  // ---- final FC + sigmoid: colg 0 WG of each clique handles its 16 batches ----
  if (colg != 0) return;
  if (w == 0) {
    u32 v = __hip_atomic_load(flg + lane, __ATOMIC_RELAXED, __HIP_MEMORY_SCOPE_AGENT);
    while (!__all(v >= (u32)T_SEQ)) {
      __builtin_amdgcn_s_sleep(1);
      v = __hip_atomic_load(flg + lane, __ATOMIC_RELAXED, __HIP_MEMORY_SCOPE_AGENT);
    }
  }
  __syncthreads();
  if (tid < 64) {
    const int bth = tid >> 2, part = tid & 3;          // 16 batches x 4 parts
    const int gb = clq * 16 + bth;
    const u64* hp = (const u64*)(hb + (size_t)gb * 1024 + part * 256);  // hb[0] = final
    const float* wp = wfc + part * 256;
    float s = 0.f;
    for (int i = 0; i < 64; ++i) {
      union { u64 u; bf16_t h[4]; } xv;
      xv.u = ldA8(hp + i);
      s += (float)xv.h[0] * wp[i * 4] + (float)xv.h[1] * wp[i * 4 + 1] +
           (float)xv.h[2] * wp[i * 4 + 2] + (float)xv.h[3] * wp[i * 4 + 3];
    }
    s += __shfl_xor(s, 1);
    s += __shfl_xor(s, 2);
    if (part == 0) out[gb] = 1.f / (1.f + __expf(-(s + bfc[0])));
  }
}

extern "C" void kernel_launch(void* const* d_in, const int* in_sizes, int n_in,
                              void* d_out, int out_size, void* d_ws, size_t ws_size,
                              hipStream_t stream) {
  const int* x = (const int*)d_in[0];
  const float* emb = (const float*)d_in[1];
  const float* wih = (const float*)d_in[2];
  const float* whh = (const float*)d_in[3];
  const float* bih = (const float*)d_in[4];
  const float* bhh = (const float*)d_in[5];
  const float* wfc = (const float*)d_in[6];
  const float* bfc = (const float*)d_in[7];
  float* out = (float*)d_out;

  char* ws = (char*)d_ws;
  bf16_t* xe = (bf16_t*)ws;                                    // 33,554,432 B
  bf16_t* wihb = (bf16_t*)(ws + 33554432);                     //  4,194,304 B
  bf16_t* hb = (bf16_t*)(ws + 33554432 + 4194304);             //  8,388,608 B
  u32* flags = (u32*)(ws + 33554432 + 4194304 + 8388608);      //      1,024 B

  hipMemsetAsync(hb, 0, 131072, stream);                       // h buffer 0 = 0
  hipMemsetAsync(flags, 0, 1024, stream);                      // all clique flags = 0
  gather_xe<<<32768, 64, 0, stream>>>(x, emb, xe);
  cvt_f32_bf16<<<1024, 256, 0, stream>>>(wih, wihb, 262144);

  void* args[] = {(void*)&xe, (void*)&wihb, (void*)&whh, (void*)&bih, (void*)&bhh,
                  (void*)&wfc, (void*)&bfc, (void*)&hb, (void*)&flags, (void*)&out};
  hipLaunchCooperativeKernel((const void*)lstm_seq, dim3(256), dim3(512), args, 0, stream);
}

// Round 12
// 2802.433 us; speedup vs baseline: 3.2763x; 1.4586x over previous
//
#include <hip/hip_runtime.h>
#include <hip/hip_bf16.h>
#include <cstdint>

typedef __bf16 bf16_t;
typedef __bf16 bf16x8 __attribute__((ext_vector_type(8)));
typedef float  f32x4  __attribute__((ext_vector_type(4)));
typedef unsigned long long u64;
typedef unsigned int u32;
typedef unsigned short u16;

#define T_SEQ 512
#define HROT  64    // h-buffer rotation depth
#define FIDX(g) ((((g) >> 3) << 5) | ((g) & 7))   // spread 64 flags over 8 cachelines

#define MFMA(a, b, c) __builtin_amdgcn_mfma_f32_16x16x32_bf16((a), (b), (c), 0, 0, 0)

static __device__ __forceinline__ u64 ldA8(const u64* p) {
  return __hip_atomic_load(p, __ATOMIC_RELAXED, __HIP_MEMORY_SCOPE_AGENT);
}
static __device__ __forceinline__ bf16x8 ld16(const bf16_t* p) {
  return *(const bf16x8*)p;
}
static __device__ __forceinline__ float sigm(float x) {
  return __builtin_amdgcn_rcpf(1.f + __expf(-x));
}
static __device__ __forceinline__ float tanh_f(float x) {
  return 2.f * __builtin_amdgcn_rcpf(1.f + __expf(-2.f * x)) - 1.f;
}

// ---------------- gather + convert: xe[t*64+b][512] = bf16(emb[x[b,t]]) ----------------
__global__ void gather_xe(const int* __restrict__ x, const float* __restrict__ emb,
                          bf16_t* __restrict__ xe) {
  const int row = blockIdx.x;            // row = t*64 + b
  const int b = row & 63, t = row >> 6;
  const int tok = x[b * 512 + t];        // x is [B][T]
  const float4* src = (const float4*)(emb + (size_t)tok * 512);
  float4 a = src[threadIdx.x * 2], c = src[threadIdx.x * 2 + 1];
  bf16x8 v;
  v[0] = (bf16_t)a.x; v[1] = (bf16_t)a.y; v[2] = (bf16_t)a.z; v[3] = (bf16_t)a.w;
  v[4] = (bf16_t)c.x; v[5] = (bf16_t)c.y; v[6] = (bf16_t)c.z; v[7] = (bf16_t)c.w;
  *(bf16x8*)(xe + (size_t)row * 512 + threadIdx.x * 8) = v;
}

// ---------------- f32 -> bf16 convert (8 elems/thread) ----------------
__global__ void cvt_f32_bf16(const float* __restrict__ s, bf16_t* __restrict__ d, int n8) {
  int i = blockIdx.x * blockDim.x + threadIdx.x;
  if (i >= n8) return;
  const float4* sp = (const float4*)s;
  float4 a = sp[2 * (size_t)i], b = sp[2 * (size_t)i + 1];
  bf16x8 v;
  v[0] = (bf16_t)a.x; v[1] = (bf16_t)a.y; v[2] = (bf16_t)a.z; v[3] = (bf16_t)a.w;
  v[4] = (bf16_t)b.x; v[5] = (bf16_t)b.y; v[6] = (bf16_t)b.z; v[7] = (bf16_t)b.w;
  *(bf16x8*)(d + 8 * (size_t)i) = v;
}

// ---------------- persistent sequential LSTM: cliques, R9-proven sync + 3 cuts ----------------
// 4 cliques x 16 batches; per clique 64 WGs x 16 cols; 8 waves K-split (h:128, xe:64).
// Producer (wave0): reduce -> fast elementwise -> 4 agent h-stores -> vmcnt(0) -> flag store
// at FIDX(colg) (flags spread over 8 cachelines to kill same-line write serialization).
// Consumer: wave1 does ONE coalesced 64-lane poll of all 64 clique flags + __all, then the
// wait-block __syncthreads fans out AND doubles as the red_s WAR guard (barrier #2 deleted).
__global__ __launch_bounds__(512, 1) void lstm_seq(
    const bf16_t* __restrict__ xe,       // [512*64][512]
    const bf16_t* __restrict__ wihb,     // [4096][512] bf16
    const float* __restrict__ whh,       // [4096][1024] f32
    const float* __restrict__ bih, const float* __restrict__ bhh,
    const float* __restrict__ wfc, const float* __restrict__ bfc,
    bf16_t* __restrict__ hb,             // [HROT][64][1024]; buffer 0 pre-zeroed
    u32* __restrict__ flags,             // [4][256] spread flags, pre-zeroed
    float* __restrict__ out) {
  __shared__ bf16_t whh_s[64][1032];     // 132,096 B
  __shared__ f32x4 red_s[7][4][64];      //  28,672 B  (total 160,768 <= 163,840)
  const int tid = threadIdx.x, bid = blockIdx.x;
  const int lane = tid & 63, w = tid >> 6;
  const int clq = (bid & 7) >> 1;                     // XCD-pair clique (locality heuristic)
  const int colg = ((bid >> 3) << 1) | (bid & 1);     // 0..63
  u32* flg = flags + clq * 256;

  // ---- stage W_hh slice f32 -> bf16 (one-time): local row r = gate*16 + c ----
  {
    const int r = tid >> 3, sub = tid & 7;            // 64 rows x 8 chunks of 128 f32
    const int grow = (r >> 4) * 1024 + colg * 16 + (r & 15);
    const float4* s = (const float4*)(whh + (size_t)grow * 1024 + sub * 128);
    bf16_t* d = &whh_s[r][sub * 128];
#pragma unroll 8
    for (int u = 0; u < 32; ++u) {
      float4 f = s[u];
      d[u * 4 + 0] = (bf16_t)f.x; d[u * 4 + 1] = (bf16_t)f.y;
      d[u * 4 + 2] = (bf16_t)f.z; d[u * 4 + 3] = (bf16_t)f.w;
    }
  }
  __syncthreads();

  const int rloc = lane & 15, kg = lane >> 4;
  const int col = colg * 16 + rloc;      // B-row / store column
  const int brow = clq * 16 + rloc;      // A-row (global batch)

  const float bI = bih[col] + bhh[col];
  const float bF = bih[1024 + col] + bhh[1024 + col];
  const float bG = bih[2048 + col] + bhh[2048 + col];
  const float bO = bih[3072 + col] + bhh[3072 + col];

  // B-frag bases: this wave's K-slice (xe: w*64, h: w*128)
  const bf16_t* wB0 = wihb + ((size_t)(0 * 1024 + col)) * 512 + w * 64 + kg * 8;
  const bf16_t* wB1 = wihb + ((size_t)(1 * 1024 + col)) * 512 + w * 64 + kg * 8;
  const bf16_t* wB2 = wihb + ((size_t)(2 * 1024 + col)) * 512 + w * 64 + kg * 8;
  const bf16_t* wB3 = wihb + ((size_t)(3 * 1024 + col)) * 512 + w * 64 + kg * 8;
  const bf16_t* hB0 = &whh_s[ 0 + rloc][w * 128 + kg * 8];
  const bf16_t* hB1 = &whh_s[16 + rloc][w * 128 + kg * 8];
  const bf16_t* hB2 = &whh_s[32 + rloc][w * 128 + kg * 8];
  const bf16_t* hB3 = &whh_s[48 + rloc][w * 128 + kg * 8];

  float cs[4] = {0.f, 0.f, 0.f, 0.f};   // cell state (wave0 lanes only)

  for (int t = 0; t < T_SEQ; ++t) {
    f32x4 A0 = {0.f, 0.f, 0.f, 0.f}, A1 = A0, A2 = A0, A3 = A0;  // i,f,g,o partials

    // ---- xe[t] @ Wih^T (own K-slice of 64): waves != 1 run it pre-wait ----
    const bf16_t* ax = xe + ((size_t)t * 64 + brow) * 512 + w * 64 + kg * 8;
#define XE_PART                                            \
    _Pragma("unroll")                                      \
    for (int kk = 0; kk < 2; ++kk) {                       \
      bf16x8 a = ld16(ax + kk * 32);                       \
      A0 = MFMA(a, ld16(wB0 + kk * 32), A0);               \
      A1 = MFMA(a, ld16(wB1 + kk * 32), A1);               \
      A2 = MFMA(a, ld16(wB2 + kk * 32), A2);               \
      A3 = MFMA(a, ld16(wB3 + kk * 32), A3);               \
    }
    if (w != 1) { XE_PART }

    // ---- wait for h(t): wave1 coalesced poll (8 lines) + __all, then fanout barrier ----
    if (t) {
      if (w == 1) {
        const u32 tgt = (u32)t;
        const u32* fp = flg + FIDX(lane);
        u32 v = __hip_atomic_load(fp, __ATOMIC_RELAXED, __HIP_MEMORY_SCOPE_AGENT);
        while (!__all(v >= tgt)) {
          __builtin_amdgcn_s_sleep(1);
          v = __hip_atomic_load(fp, __ATOMIC_RELAXED, __HIP_MEMORY_SCOPE_AGENT);
        }
      }
      __syncthreads();                   // fanout + red_s WAR guard (replaces barrier #2)
      asm volatile("" ::: "memory");     // pin h loads below the barrier
    }
    if (w == 1) { XE_PART }
#undef XE_PART

    // ---- h(t) @ Whh^T (own K-slice of 128): plain nt loads, rotated buffer ----
    const bf16_t* ah = hb + (size_t)(t & (HROT - 1)) * 65536 +
                       (size_t)brow * 1024 + w * 128 + kg * 8;
#pragma unroll
    for (int kk = 0; kk < 4; ++kk) {
      bf16x8 a = __builtin_nontemporal_load((const bf16x8*)(ah + kk * 32));
      A0 = MFMA(a, ld16(hB0 + kk * 32), A0);
      A1 = MFMA(a, ld16(hB1 + kk * 32), A1);
      A2 = MFMA(a, ld16(hB2 + kk * 32), A2);
      A3 = MFMA(a, ld16(hB3 + kk * 32), A3);
    }

    // ---- K-reduce: waves 1-7 dump partials; wave0 sums after the barrier ----
    if (w) {
      red_s[w - 1][0][lane] = A0; red_s[w - 1][1][lane] = A1;
      red_s[w - 1][2][lane] = A2; red_s[w - 1][3][lane] = A3;
    }
    __syncthreads();                     // partials visible (only barrier besides fanout)
    if (w == 0) {
#pragma unroll
      for (int q = 0; q < 7; ++q) {
        A0 += red_s[q][0][lane]; A1 += red_s[q][1][lane];
        A2 += red_s[q][2][lane]; A3 += red_s[q][3][lane];
      }
      // ---- fast elementwise + h-store + drain + spread flag ----
      u16* hn = (u16*)(hb + (size_t)((t + 1) & (HROT - 1)) * 65536) +
                (size_t)(clq * 16 + kg * 4) * 1024 + col;
#pragma unroll
      for (int r = 0; r < 4; ++r) {
        const float gi = A0[r] + bI, gf = A1[r] + bF, gg = A2[r] + bG, go = A3[r] + bO;
        const float ii = sigm(gi), ff = sigm(gf), oo = sigm(go);
        cs[r] = ff * cs[r] + ii * tanh_f(gg);
        const float hv = oo * tanh_f(cs[r]);
        const bf16_t hvb = (bf16_t)hv;
        __hip_atomic_store(hn + (size_t)r * 1024, __builtin_bit_cast(u16, hvb),
                           __ATOMIC_RELAXED, __HIP_MEMORY_SCOPE_AGENT);
      }
      asm volatile("s_waitcnt vmcnt(0)" ::: "memory");  // only wave0 stores h
      if (lane == 0)
        __hip_atomic_store(flg + FIDX(colg), (u32)(t + 1), __ATOMIC_RELAXED,
                           __HIP_MEMORY_SCOPE_AGENT);
    }
    // waves 1-7 run ahead into step t+1; their next red_s dump is gated by the
    // fanout barrier, which wave0 reaches only after its red_s reads. WAR-safe.
  }

  // ---- final FC + sigmoid: colg 0 WG of each clique handles its 16 batches ----
  if (colg != 0) return;
  if (w == 0) {
    const u32* fp = flg + FIDX(lane);
    u32 v = __hip_atomic_load(fp, __ATOMIC_RELAXED, __HIP_MEMORY_SCOPE_AGENT);
    while (!__all(v >= (u32)T_SEQ)) {
      __builtin_amdgcn_s_sleep(1);
      v = __hip_atomic_load(fp, __ATOMIC_RELAXED, __HIP_MEMORY_SCOPE_AGENT);
    }
  }
  __syncthreads();
  if (tid < 64) {
    const int bth = tid >> 2, part = tid & 3;          // 16 batches x 4 parts
    const int gb = clq * 16 + bth;
    const u64* hp = (const u64*)(hb + (size_t)gb * 1024 + part * 256);  // hb[0] = final
    const float* wp = wfc + part * 256;
    float s = 0.f;
    for (int i = 0; i < 64; ++i) {
      union { u64 u; bf16_t h[4]; } xv;
      xv.u = ldA8(hp + i);
      s += (float)xv.h[0] * wp[i * 4] + (float)xv.h[1] * wp[i * 4 + 1] +
           (float)xv.h[2] * wp[i * 4 + 2] + (float)xv.h[3] * wp[i * 4 + 3];
    }
    s += __shfl_xor(s, 1);
    s += __shfl_xor(s, 2);
    if (part == 0) out[gb] = sigm(s + bfc[0]);
  }
}

extern "C" void kernel_launch(void* const* d_in, const int* in_sizes, int n_in,
                              void* d_out, int out_size, void* d_ws, size_t ws_size,
                              hipStream_t stream) {
  const int* x = (const int*)d_in[0];
  const float* emb = (const float*)d_in[1];
  const float* wih = (const float*)d_in[2];
  const float* whh = (const float*)d_in[3];
  const float* bih = (const float*)d_in[4];
  const float* bhh = (const float*)d_in[5];
  const float* wfc = (const float*)d_in[6];
  const float* bfc = (const float*)d_in[7];
  float* out = (float*)d_out;

  char* ws = (char*)d_ws;
  bf16_t* xe = (bf16_t*)ws;                                    // 33,554,432 B
  bf16_t* wihb = (bf16_t*)(ws + 33554432);                     //  4,194,304 B
  bf16_t* hb = (bf16_t*)(ws + 33554432 + 4194304);             //  8,388,608 B
  u32* flags = (u32*)(ws + 33554432 + 4194304 + 8388608);      //      4,096 B

  hipMemsetAsync(hb, 0, 131072, stream);                       // h buffer 0 = 0
  hipMemsetAsync(flags, 0, 4096, stream);                      // all spread flags = 0
  gather_xe<<<32768, 64, 0, stream>>>(x, emb, xe);
  cvt_f32_bf16<<<1024, 256, 0, stream>>>(wih, wihb, 262144);

  void* args[] = {(void*)&xe, (void*)&wihb, (void*)&whh, (void*)&bih, (void*)&bhh,
                  (void*)&wfc, (void*)&bfc, (void*)&hb, (void*)&flags, (void*)&out};
  hipLaunchCooperativeKernel((const void*)lstm_seq, dim3(256), dim3(512), args, 0, stream);
}